// Round 8
// baseline (56.235 us; speedup 1.0000x reference)
//
#include <hip/hip_runtime.h>
#include <cstdint>

// QuantumLatentLayer via MFMA: out[b,q] = cos(a)cos(th_q) - sin(a)cos(phi_q)sin(th_q),
// a = latent(32768x2048) . W^T(24x2048) + b.
// R7 (52.9us): MFMA kills W-delivery; main ~48us vs 38.3us HBM floor at only
// 2 waves/SIMD (grid-limited TLP). v8: k-split 2 across wave pairs -> 4096
// waves = 4 waves/SIMD, 4-deep pipeline (32 tiles/wave), one-time 4KB LDS
// reduction. Latent hi/lo bf16 split (err ~ W-rounding only, absmax 0.0078).
// W prepacked per-fragment; bias+trig fused in epilogue.

#define NQ 24
#define LDIM 2048
#define BATCH 32768
#define NT 32             // k-tiles per wave (half of 64)

typedef __attribute__((ext_vector_type(8))) short bf16x8;
typedef __attribute__((ext_vector_type(4))) float f32x4;

union U4 { uint4 u; bf16x8 s; };

__device__ __forceinline__ uint cvt_pk_bf16(float lo, float hi) {
    uint r;
    asm("v_cvt_pk_bf16_f32 %0, %1, %2" : "=v"(r) : "v"(lo), "v"(hi));
    return r;
}

struct Stage { float4 a0, a1; uint4 b0, b1; };

// Issue one k-tile's loads (4 VMEM insts). A: lane -> row=lane&15, k=kgrp*8..+7;
// the wave's a0+a1 pair covers 16 rows x 32 k = 16 full 128B lines (no waste).
__device__ __forceinline__ void issue(Stage& s, const float* ap, const uint4* bp, int t) {
    s.a0 = *(const float4*)(ap + t * 32);
    s.a1 = *(const float4*)(ap + t * 32 + 4);
    s.b0 = bp[t * 128];        // qtile 0 fragment
    s.b1 = bp[t * 128 + 64];   // qtile 1 fragment
}

__device__ __forceinline__ void computeS(const Stage& s, f32x4& c0, f32x4& c1) {
    // hi/lo bf16 split of the 8 fp32 A elements (RNE via v_cvt_pk_bf16_f32)
    uint h0 = cvt_pk_bf16(s.a0.x, s.a0.y);
    uint h1 = cvt_pk_bf16(s.a0.z, s.a0.w);
    uint h2 = cvt_pk_bf16(s.a1.x, s.a1.y);
    uint h3 = cvt_pk_bf16(s.a1.z, s.a1.w);
    float r0 = __uint_as_float(h0 << 16), r1 = __uint_as_float(h0 & 0xFFFF0000u);
    float r2 = __uint_as_float(h1 << 16), r3 = __uint_as_float(h1 & 0xFFFF0000u);
    float r4 = __uint_as_float(h2 << 16), r5 = __uint_as_float(h2 & 0xFFFF0000u);
    float r6 = __uint_as_float(h3 << 16), r7 = __uint_as_float(h3 & 0xFFFF0000u);
    uint l0 = cvt_pk_bf16(s.a0.x - r0, s.a0.y - r1);
    uint l1 = cvt_pk_bf16(s.a0.z - r2, s.a0.w - r3);
    uint l2 = cvt_pk_bf16(s.a1.x - r4, s.a1.y - r5);
    uint l3 = cvt_pk_bf16(s.a1.z - r6, s.a1.w - r7);
    U4 ah, al, b0, b1;
    ah.u = make_uint4(h0, h1, h2, h3);
    al.u = make_uint4(l0, l1, l2, l3);
    b0.u = s.b0;
    b1.u = s.b1;
    c0 = __builtin_amdgcn_mfma_f32_16x16x32_bf16(ah.s, b0.s, c0, 0, 0, 0);
    c1 = __builtin_amdgcn_mfma_f32_16x16x32_bf16(ah.s, b1.s, c1, 0, 0, 0);
    c0 = __builtin_amdgcn_mfma_f32_16x16x32_bf16(al.s, b0.s, c0, 0, 0, 0);
    c1 = __builtin_amdgcn_mfma_f32_16x16x32_bf16(al.s, b1.s, c1, 0, 0, 0);
}

__global__ __launch_bounds__(256, 4) void qll_main(
    const float* __restrict__ latent,
    const uint4* __restrict__ wb,     // prepacked W fragments, bf16, 128 KB
    const float* __restrict__ bvec,
    const float* __restrict__ ctv,    // cos(theta)
    const float* __restrict__ csv,    // cos(phi)*sin(theta)
    float* __restrict__ out)
{
    // wave pair (rtile, khalf): same 16 rows, disjoint k halves.
    __shared__ float lred[2][8][64];   // 4 KB, conflict-free [j][lane] layout

    const int tid   = threadIdx.x;
    const int wave  = tid >> 6;
    const int lane  = tid & 63;
    const int khalf = wave & 1;
    const int rtile = wave >> 1;
    const int mrow  = lane & 15;
    const int kgrp  = lane >> 4;
    const int row0  = (blockIdx.x * 2 + rtile) * 16;

    const float* ap = latent + (size_t)(row0 + mrow) * LDIM + khalf * (NT * 32) + kgrp * 8;
    const uint4* bp = wb + (size_t)khalf * NT * 128 + lane;

    f32x4 c0 = {0.f, 0.f, 0.f, 0.f};
    f32x4 c1 = {0.f, 0.f, 0.f, 0.f};

    // 4-deep pipeline, named stages (static indexing). Register loads: compiler
    // inserts exact counted vmcnt per use (no LDS staging anywhere).
    Stage S0, S1, S2, S3;
    issue(S0, ap, bp, 0);
    issue(S1, ap, bp, 1);
    issue(S2, ap, bp, 2);
    issue(S3, ap, bp, 3);

    #pragma unroll 1
    for (int t = 0; t <= NT - 8; t += 4) {   // t=0..24: compute 0..27, issue 4..31
        computeS(S0, c0, c1); issue(S0, ap, bp, t + 4);
        computeS(S1, c0, c1); issue(S1, ap, bp, t + 5);
        computeS(S2, c0, c1); issue(S2, ap, bp, t + 6);
        computeS(S3, c0, c1); issue(S3, ap, bp, t + 7);
    }
    computeS(S0, c0, c1);   // 28
    computeS(S1, c0, c1);   // 29
    computeS(S2, c0, c1);   // 30
    computeS(S3, c0, c1);   // 31

    // Cross-k-half reduction: odd waves publish, even waves consume.
    if (khalf) {
        #pragma unroll
        for (int j = 0; j < 4; j++) {
            lred[rtile][j][lane]     = c0[j];
            lred[rtile][4 + j][lane] = c1[j];
        }
    }
    __syncthreads();
    if (!khalf) {
        #pragma unroll
        for (int j = 0; j < 4; j++) {
            c0[j] += lred[rtile][j][lane];
            c1[j] += lred[rtile][4 + j][lane];
        }
        // Epilogue: C/D layout (m89): col q = (lane&15) + 16*qt, row = kgrp*4 + r.
        #pragma unroll
        for (int qt = 0; qt < 2; qt++) {
            const int q = qt * 16 + mrow;
            const bool valid = (q < NQ);
            const float bv = valid ? bvec[q] : 0.f;
            const float ct = valid ? ctv[q]  : 0.f;
            const float cs = valid ? csv[q]  : 0.f;
            const f32x4 c = qt ? c1 : c0;
            #pragma unroll
            for (int r = 0; r < 4; r++) {
                const int row = row0 + kgrp * 4 + r;
                const float a = c[r] + bv;
                float s, co;
                __sincosf(a, &s, &co);
                if (valid) out[(size_t)row * NQ + q] = co * ct - s * cs;
            }
        }
    }
}

// Prep: pack W into per-fragment bf16 layout. Fragment (kt, qt): 64 lanes x 16 B;
// lane l supplies q = qt*16 + (l&15), k = kt*32 + (l>>4)*8 + e (e=0..7), zero-pad
// q>=24. Flat ushort index = ((kt*2 + qt)*64 + l)*8 + e. Also ctcs[0..23]=cos(th),
// ctcs[24..47]=cos(phi)*sin(th).
__global__ __launch_bounds__(256) void qll_prep(
    const float* __restrict__ W, const float* __restrict__ params,
    ushort* __restrict__ wb, float* __restrict__ ctcs)
{
    const int idx = blockIdx.x * 256 + threadIdx.x;   // 0..65535
    const int kt  = idx >> 10;
    const int rem = idx & 1023;
    const int qt  = rem >> 9;
    const int l   = (rem >> 3) & 63;
    const int e   = rem & 7;
    const int q   = qt * 16 + (l & 15);
    const int k   = kt * 32 + (l >> 4) * 8 + e;
    float v = (q < NQ) ? W[q * LDIM + k] : 0.f;
    uint u = __float_as_uint(v);
    wb[idx] = (ushort)((u + 0x7FFF + ((u >> 16) & 1)) >> 16);   // RNE bf16
    if (idx < NQ) {
        float phi = params[3 * idx + 0];
        float th  = params[3 * idx + 1];
        ctcs[idx]      = cosf(th);
        ctcs[NQ + idx] = cosf(phi) * sinf(th);
    }
}

extern "C" void kernel_launch(void* const* d_in, const int* in_sizes, int n_in,
                              void* d_out, int out_size, void* d_ws, size_t ws_size,
                              hipStream_t stream) {
    (void)in_sizes; (void)n_in; (void)out_size; (void)ws_size;
    const float* latent = (const float*)d_in[0];
    const float* W      = (const float*)d_in[1];
    const float* bvec   = (const float*)d_in[2];
    const float* params = (const float*)d_in[3];
    float* out  = (float*)d_out;
    ushort* wb  = (ushort*)d_ws;                     // 65536 bf16 = 128 KB
    float* ctcs = (float*)d_ws + 32768;              // 48 floats

    hipLaunchKernelGGL(qll_prep, dim3(256), dim3(256), 0, stream,
                       W, params, wb, ctcs);
    hipLaunchKernelGGL(qll_main, dim3(BATCH / 32), dim3(256), 0, stream,
                       latent, (const uint4*)wb, bvec, ctcs, ctcs + NQ, out);
}

// Round 9
// 55.185 us; speedup vs baseline: 1.0190x; 1.0190x over previous
//
#include <hip/hip_runtime.h>
#include <cstdint>

// QuantumLatentLayer via MFMA: out[b,q] = cos(a)cos(th_q) - sin(a)cos(phi_q)sin(th_q),
// a = latent(32768x2048) . W^T(24x2048) + b.
// R7 (52.9us): MFMA removes W-delivery; 16 rows x 32 k per wave = 16 full
// cachelines per A-load pair, zero LDS, compiler-managed counted vmcnt.
// R8 lesson: k-split (4 waves/SIMD) REGRESSED (56.2) -> TLP is not the
// residual; reverted. v9: R7 + 6-deep pipeline (in-flight/wave 8->20 KB,
// load-to-use distance 5 phases) to absorb HBM/L2 return-latency jitter at
// the grid-capped 2 waves/SIMD. VGPR ~135 < 256 (occupancy grid-capped, free).
// Latent hi/lo bf16 split keeps absmax ~0.0078 << 0.02.

#define NQ 24
#define LDIM 2048
#define BATCH 32768
#define NKT 64            // 2048 / 32 k-tiles

typedef __attribute__((ext_vector_type(8))) short bf16x8;
typedef __attribute__((ext_vector_type(4))) float f32x4;

union U4 { uint4 u; bf16x8 s; };

__device__ __forceinline__ uint cvt_pk_bf16(float lo, float hi) {
    uint r;
    asm("v_cvt_pk_bf16_f32 %0, %1, %2" : "=v"(r) : "v"(lo), "v"(hi));
    return r;
}

struct Stage { float4 a0, a1; uint4 b0, b1; };

// Issue one k-tile's loads (4 VMEM insts). A: lane -> row=lane&15, k=kgrp*8..+7;
// the wave's a0+a1 pair covers 16 rows x 32 k = 16 full 128B lines (no waste).
__device__ __forceinline__ void issue(Stage& s, const float* ap, const uint4* bp, int t) {
    s.a0 = *(const float4*)(ap + t * 32);
    s.a1 = *(const float4*)(ap + t * 32 + 4);
    s.b0 = bp[t * 128];        // qtile 0 fragment
    s.b1 = bp[t * 128 + 64];   // qtile 1 fragment
}

__device__ __forceinline__ void computeS(const Stage& s, f32x4& c0, f32x4& c1) {
    // hi/lo bf16 split of the 8 fp32 A elements (RNE via v_cvt_pk_bf16_f32)
    uint h0 = cvt_pk_bf16(s.a0.x, s.a0.y);
    uint h1 = cvt_pk_bf16(s.a0.z, s.a0.w);
    uint h2 = cvt_pk_bf16(s.a1.x, s.a1.y);
    uint h3 = cvt_pk_bf16(s.a1.z, s.a1.w);
    float r0 = __uint_as_float(h0 << 16), r1 = __uint_as_float(h0 & 0xFFFF0000u);
    float r2 = __uint_as_float(h1 << 16), r3 = __uint_as_float(h1 & 0xFFFF0000u);
    float r4 = __uint_as_float(h2 << 16), r5 = __uint_as_float(h2 & 0xFFFF0000u);
    float r6 = __uint_as_float(h3 << 16), r7 = __uint_as_float(h3 & 0xFFFF0000u);
    uint l0 = cvt_pk_bf16(s.a0.x - r0, s.a0.y - r1);
    uint l1 = cvt_pk_bf16(s.a0.z - r2, s.a0.w - r3);
    uint l2 = cvt_pk_bf16(s.a1.x - r4, s.a1.y - r5);
    uint l3 = cvt_pk_bf16(s.a1.z - r6, s.a1.w - r7);
    U4 ah, al, b0, b1;
    ah.u = make_uint4(h0, h1, h2, h3);
    al.u = make_uint4(l0, l1, l2, l3);
    b0.u = s.b0;
    b1.u = s.b1;
    c0 = __builtin_amdgcn_mfma_f32_16x16x32_bf16(ah.s, b0.s, c0, 0, 0, 0);
    c1 = __builtin_amdgcn_mfma_f32_16x16x32_bf16(ah.s, b1.s, c1, 0, 0, 0);
    c0 = __builtin_amdgcn_mfma_f32_16x16x32_bf16(al.s, b0.s, c0, 0, 0, 0);
    c1 = __builtin_amdgcn_mfma_f32_16x16x32_bf16(al.s, b1.s, c1, 0, 0, 0);
}

__global__ __launch_bounds__(256, 2) void qll_main(
    const float* __restrict__ latent,
    const uint4* __restrict__ wb,     // prepacked W fragments, bf16, 128 KB
    const float* __restrict__ bvec,
    const float* __restrict__ ctv,    // cos(theta)
    const float* __restrict__ csv,    // cos(phi)*sin(theta)
    float* __restrict__ out)
{
    const int tid  = threadIdx.x;
    const int wave = tid >> 6;
    const int lane = tid & 63;
    const int mrow = lane & 15;
    const int kgrp = lane >> 4;
    const int row0 = (blockIdx.x * 4 + wave) * 16;

    const float* ap = latent + (size_t)(row0 + mrow) * LDIM + kgrp * 8;
    const uint4* bp = wb + lane;

    f32x4 c0 = {0.f, 0.f, 0.f, 0.f};
    f32x4 c1 = {0.f, 0.f, 0.f, 0.f};

    // 6-deep pipeline, named stages (static indexing, rule #20). Register
    // loads: compiler inserts exact counted vmcnt before each stage's use,
    // leaving 5 stages (20 KB/wave) in flight.
    Stage S0, S1, S2, S3, S4, S5;
    issue(S0, ap, bp, 0);
    issue(S1, ap, bp, 1);
    issue(S2, ap, bp, 2);
    issue(S3, ap, bp, 3);
    issue(S4, ap, bp, 4);
    issue(S5, ap, bp, 5);

    #pragma unroll 1
    for (int t = 0; t <= NKT - 16; t += 6) {  // t=0..48: compute 0..53, issue 6..59
        computeS(S0, c0, c1); issue(S0, ap, bp, t + 6);
        computeS(S1, c0, c1); issue(S1, ap, bp, t + 7);
        computeS(S2, c0, c1); issue(S2, ap, bp, t + 8);
        computeS(S3, c0, c1); issue(S3, ap, bp, t + 9);
        computeS(S4, c0, c1); issue(S4, ap, bp, t + 10);
        computeS(S5, c0, c1); issue(S5, ap, bp, t + 11);
    }
    // tiles 54..59 compute + issue 60..63; then drain 60..63.
    computeS(S0, c0, c1); issue(S0, ap, bp, 60);
    computeS(S1, c0, c1); issue(S1, ap, bp, 61);
    computeS(S2, c0, c1); issue(S2, ap, bp, 62);
    computeS(S3, c0, c1); issue(S3, ap, bp, 63);
    computeS(S4, c0, c1);
    computeS(S5, c0, c1);
    computeS(S0, c0, c1);   // 60
    computeS(S1, c0, c1);   // 61
    computeS(S2, c0, c1);   // 62
    computeS(S3, c0, c1);   // 63

    // Epilogue: C/D layout (m89): col q = (lane&15) + 16*qt, row = kgrp*4 + r.
    #pragma unroll
    for (int qt = 0; qt < 2; qt++) {
        const int q = qt * 16 + mrow;
        const bool valid = (q < NQ);
        const float bv = valid ? bvec[q] : 0.f;
        const float ct = valid ? ctv[q]  : 0.f;
        const float cs = valid ? csv[q]  : 0.f;
        const f32x4 c = qt ? c1 : c0;
        #pragma unroll
        for (int r = 0; r < 4; r++) {
            const int row = row0 + kgrp * 4 + r;
            const float a = c[r] + bv;
            float s, co;
            __sincosf(a, &s, &co);
            if (valid) out[(size_t)row * NQ + q] = co * ct - s * cs;
        }
    }
}

// Prep: pack W into per-fragment bf16 layout. Fragment (kt, qt): 64 lanes x 16 B;
// lane l supplies q = qt*16 + (l&15), k = kt*32 + (l>>4)*8 + e (e=0..7), zero-pad
// q>=24. Flat ushort index = ((kt*2 + qt)*64 + l)*8 + e. Also ctcs[0..23]=cos(th),
// ctcs[24..47]=cos(phi)*sin(th).
__global__ __launch_bounds__(256) void qll_prep(
    const float* __restrict__ W, const float* __restrict__ params,
    ushort* __restrict__ wb, float* __restrict__ ctcs)
{
    const int idx = blockIdx.x * 256 + threadIdx.x;   // 0..65535
    const int kt  = idx >> 10;
    const int rem = idx & 1023;
    const int qt  = rem >> 9;
    const int l   = (rem >> 3) & 63;
    const int e   = rem & 7;
    const int q   = qt * 16 + (l & 15);
    const int k   = kt * 32 + (l >> 4) * 8 + e;
    float v = (q < NQ) ? W[q * LDIM + k] : 0.f;
    uint u = __float_as_uint(v);
    wb[idx] = (ushort)((u + 0x7FFF + ((u >> 16) & 1)) >> 16);   // RNE bf16
    if (idx < NQ) {
        float phi = params[3 * idx + 0];
        float th  = params[3 * idx + 1];
        ctcs[idx]      = cosf(th);
        ctcs[NQ + idx] = cosf(phi) * sinf(th);
    }
}

extern "C" void kernel_launch(void* const* d_in, const int* in_sizes, int n_in,
                              void* d_out, int out_size, void* d_ws, size_t ws_size,
                              hipStream_t stream) {
    (void)in_sizes; (void)n_in; (void)out_size; (void)ws_size;
    const float* latent = (const float*)d_in[0];
    const float* W      = (const float*)d_in[1];
    const float* bvec   = (const float*)d_in[2];
    const float* params = (const float*)d_in[3];
    float* out  = (float*)d_out;
    ushort* wb  = (ushort*)d_ws;                     // 65536 bf16 = 128 KB
    float* ctcs = (float*)d_ws + 32768;              // 48 floats

    hipLaunchKernelGGL(qll_prep, dim3(256), dim3(256), 0, stream,
                       W, params, wb, ctcs);
    hipLaunchKernelGGL(qll_main, dim3(BATCH / 64), dim3(256), 0, stream,
                       latent, (const uint4*)wb, bvec, ctcs, ctcs + NQ, out);
}